// Round 11
// baseline (125.111 us; speedup 1.0000x reference)
//
#include <hip/hip_runtime.h>
#include <hip/hip_bf16.h>

typedef __attribute__((ext_vector_type(8))) short bf16x8;
typedef __attribute__((ext_vector_type(4))) float f32x4;

#define N_TOT 8192
#define B_IN  4096
#define D_K   256
#define NSPLIT 16   // col splits of 512
#define NRG    128  // row groups of 64
#define EXPC 2.8853900817779268f  // 2/ln2

__device__ __forceinline__ unsigned short f2bf(float x) {
  unsigned u = __float_as_uint(x);
  u = (u + 0x7FFFu + ((u >> 16) & 1u)) >> 16;
  return (unsigned short)u;
}
__device__ __forceinline__ float bf2f(unsigned short u) {
  return __uint_as_float(((unsigned)u) << 16);
}

// Normalize each (b,v) row, write bf16 X in anchor order (n = v*B + b), fill labN, histogram cnt.
__global__ void norm_kernel(const float* __restrict__ feat,
                            const int* __restrict__ labels,
                            unsigned short* __restrict__ X,
                            int* __restrict__ labN,
                            int* __restrict__ cnt) {
  int n = blockIdx.x * 4 + (threadIdx.x >> 6);
  int l = threadIdx.x & 63;
  int b = n & (B_IN - 1);
  int v = n >> 12;
  const float4 f = *reinterpret_cast<const float4*>(feat + (size_t)(b * 2 + v) * D_K + l * 4);
  float s = f.x * f.x + f.y * f.y + f.z * f.z + f.w * f.w;
#pragma unroll
  for (int m = 1; m < 64; m <<= 1) s += __shfl_xor(s, m);
  float scale = 1.0f / fmaxf(sqrtf(s), 1e-12f);
  ushort4 o;
  o.x = f2bf(f.x * scale);
  o.y = f2bf(f.y * scale);
  o.z = f2bf(f.z * scale);
  o.w = f2bf(f.w * scale);
  *reinterpret_cast<ushort4*>(X + (size_t)n * D_K + l * 4) = o;
  if (l == 0) {
    int lb = labels[b];
    labN[n] = lb;
    if (n < B_IN) atomicAdd(&cnt[lb], 1);  // integer atomic: deterministic
  }
}

// Class-sum vectors: G[c] = sum of normalized rows (both views) with label c.
// 250 blocks x 256 threads; wave w handles class blockIdx*4+w.
__global__ void classsum_kernel(const unsigned short* __restrict__ X,
                                const int* __restrict__ labels,
                                float* __restrict__ G) {
  const int c = blockIdx.x * 4 + (threadIdx.x >> 6);
  const int l = threadIdx.x & 63;
  float a0 = 0.f, a1 = 0.f, a2 = 0.f, a3 = 0.f;
  for (int it = 0; it < B_IN / 64; ++it) {
    unsigned long long m = __ballot(labels[it * 64 + l] == c);
    while (m) {
      int bit = __ffsll((long long)m) - 1;
      m &= m - 1;
      int b = it * 64 + bit;
      ushort4 r0 = *reinterpret_cast<const ushort4*>(X + (size_t)b * D_K + l * 4);
      ushort4 r1 = *reinterpret_cast<const ushort4*>(X + (size_t)(b + B_IN) * D_K + l * 4);
      a0 += bf2f(r0.x) + bf2f(r1.x);
      a1 += bf2f(r0.y) + bf2f(r1.y);
      a2 += bf2f(r0.z) + bf2f(r1.z);
      a3 += bf2f(r0.w) + bf2f(r1.w);
    }
  }
  float4 o = {a0, a1, a2, a3};
  *reinterpret_cast<float4*>(G + (size_t)c * D_K + l * 4) = o;
}

// Main: 2048 single-wave blocks (128 row-groups x 16 col-splits). ZERO LDS, ZERO barriers.
// Wave owns 64 rows x 512 cols; A PINNED in 128 VGPRs via opaque asm redefinition
// (prevents the compiler rematerializing the loads inside the loop — R10's failure);
// B-frags straight from L2 with the same (row,k) lane mapping (k-perm cancels in A.B^T).
__global__ __launch_bounds__(64, 2) void main_kernel(const unsigned short* __restrict__ X,
                                                     float* __restrict__ SpA) {
  const int l = threadIdx.x;
  const int lm = l & 15, lh = l >> 4;
  const int rg = blockIdx.x >> 4;   // 128 row groups of 64
  const int cs = blockIdx.x & 15;   // 16 col splits of 512
  const int wrow = rg * 64;
  const int cbase = cs * 512;

  // A fragments: rows wrow + fi*16 + lm, elems kk*32 + lh*8 .. +7. Pinned resident.
  bf16x8 a[4][8];
#pragma unroll
  for (int fi = 0; fi < 4; ++fi)
#pragma unroll
    for (int kk = 0; kk < 8; ++kk) {
      a[fi][kk] = *reinterpret_cast<const bf16x8*>(
          X + (size_t)(wrow + fi * 16 + lm) * D_K + kk * 32 + lh * 8);
      asm volatile("" : "+v"(a[fi][kk]));  // opaque redef: no remat, stays in VGPRs
    }

  float S[4][4] = {};

  for (int ct = 0; ct < 16; ++ct) {
    // B rows (= C cols) for this 32-col tile: ctb + lm and ctb + 16 + lm
    const unsigned short* Bp = X + (size_t)(cbase + ct * 32 + lm) * D_K + lh * 8;
    f32x4 acc[4][2];
#pragma unroll
    for (int fi = 0; fi < 4; ++fi) {
      acc[fi][0] = (f32x4){0.f, 0.f, 0.f, 0.f};
      acc[fi][1] = (f32x4){0.f, 0.f, 0.f, 0.f};
    }
#pragma unroll
    for (int kk = 0; kk < 8; ++kk) {
      bf16x8 b0 = *reinterpret_cast<const bf16x8*>(Bp + kk * 32);
      bf16x8 b1 = *reinterpret_cast<const bf16x8*>(Bp + 16 * D_K + kk * 32);
#pragma unroll
      for (int fi = 0; fi < 4; ++fi) {
        acc[fi][0] = __builtin_amdgcn_mfma_f32_16x16x32_bf16(a[fi][kk], b0, acc[fi][0], 0, 0, 0);
        acc[fi][1] = __builtin_amdgcn_mfma_f32_16x16x32_bf16(a[fi][kk], b1, acc[fi][1], 0, 0, 0);
      }
    }
    // epilogue: S += exp(2v-2) = exp2(C*v - C) over ALL cols (self removed in reduce)
#pragma unroll
    for (int fi = 0; fi < 4; ++fi)
#pragma unroll
      for (int fj = 0; fj < 2; ++fj)
#pragma unroll
        for (int r = 0; r < 4; ++r)
          S[fi][r] += exp2f(fmaf(acc[fi][fj][r], EXPC, -EXPC));
  }

  // reduce across the 16 lm lanes; write Sp transposed [row][split] for coalesced reduceA
#pragma unroll
  for (int fi = 0; fi < 4; ++fi)
#pragma unroll
    for (int r = 0; r < 4; ++r) {
      float s = S[fi][r];
#pragma unroll
      for (int m = 1; m < 16; m <<= 1) s += __shfl_xor(s, m);
      if (lm == 0) {
        int row = wrow + fi * 16 + lh * 4 + r;
        SpA[(size_t)row * NSPLIT + cs] = s;
      }
    }
}

// Per-anchor loss: one wave per n (16 n's per wave). 128 blocks x 256 thr.
__global__ void reduceA_kernel(const float* __restrict__ Sp,
                               const unsigned short* __restrict__ X,
                               const float* __restrict__ G,
                               const int* __restrict__ labN,
                               const int* __restrict__ cnt,
                               float* __restrict__ tmp) {
  const int w = threadIdx.x >> 6, l = threadIdx.x & 63;
  const int gw = blockIdx.x * 4 + w;  // 0..511
  for (int k = 0; k < 16; ++k) {
    int n = gw * 16 + k;
    int lab = labN[n];
    ushort4 xr = *reinterpret_cast<const ushort4*>(X + (size_t)n * D_K + l * 4);
    float4 gr = *reinterpret_cast<const float4*>(G + (size_t)lab * D_K + l * 4);
    float dp = bf2f(xr.x) * gr.x + bf2f(xr.y) * gr.y + bf2f(xr.z) * gr.z + bf2f(xr.w) * gr.w;
    float sl = (l < NSPLIT) ? Sp[(size_t)n * NSPLIT + l] : 0.f;
#pragma unroll
    for (int m = 1; m < 64; m <<= 1) {
      dp += __shfl_xor(dp, m);
      sl += __shfl_xor(sl, m);
    }
    if (l == 0) {
      float S = sl - 1.0f;            // remove self exp term (exp(2*selfdot-2) ~= 1)
      float P = 2.0f * dp - 2.0f;     // G includes self; remove self logit (~= 2)
      float np = (float)(2 * cnt[lab] - 1);
      tmp[n] = logf(S) + 2.0f - P / np;
    }
  }
}

__global__ void reduceB_kernel(const float* __restrict__ tmp, float* __restrict__ out) {
  __shared__ float red[4];
  int tid = threadIdx.x;
  float acc = 0.f;
  for (int i = tid; i < N_TOT; i += 256) acc += tmp[i];
#pragma unroll
  for (int m = 1; m < 64; m <<= 1) acc += __shfl_xor(acc, m);
  if ((tid & 63) == 0) red[tid >> 6] = acc;
  __syncthreads();
  if (tid == 0) out[0] = (red[0] + red[1] + red[2] + red[3]) * (1.0f / (float)N_TOT);
}

extern "C" void kernel_launch(void* const* d_in, const int* in_sizes, int n_in,
                              void* d_out, int out_size, void* d_ws, size_t ws_size,
                              hipStream_t stream) {
  const float* feat = (const float*)d_in[0];
  const int* labels = (const int*)d_in[1];
  char* ws = (char*)d_ws;
  unsigned short* X = (unsigned short*)ws;   // 4 MB
  int* labN = (int*)(ws + 4194304);          // 32 KB
  int* cnt = (int*)(ws + 4227072);           // 4 KB
  float* Sp = (float*)(ws + 4231168);        // 8192*16*4 = 512 KB
  float* G = (float*)(ws + 4755456);         // 1000*256*4 = 1000 KB
  float* tmp = (float*)(ws + 5779456);       // 32 KB
  float* out = (float*)d_out;

  hipMemsetAsync(cnt, 0, 4096, stream);
  norm_kernel<<<2048, 256, 0, stream>>>(feat, labels, X, labN, cnt);
  classsum_kernel<<<250, 256, 0, stream>>>(X, labels, G);
  main_kernel<<<NRG * NSPLIT, 64, 0, stream>>>(X, Sp);
  reduceA_kernel<<<128, 256, 0, stream>>>(Sp, X, G, labN, cnt, tmp);
  reduceB_kernel<<<1, 256, 0, stream>>>(tmp, out);
}

// Round 12
// 107.475 us; speedup vs baseline: 1.1641x; 1.1641x over previous
//
#include <hip/hip_runtime.h>
#include <hip/hip_bf16.h>

typedef __attribute__((ext_vector_type(8))) short bf16x8;
typedef __attribute__((ext_vector_type(4))) float f32x4;

#define N_TOT 8192
#define B_IN  4096
#define D_K   256
#define NSPLIT 32   // col splits of 256
#define NRG    32   // row groups of 256
#define EXPC 2.8853900817779268f  // 2/ln2

typedef __attribute__((address_space(3))) unsigned int lds_uint;
typedef __attribute__((address_space(1))) const unsigned int glob_uint;

__device__ __forceinline__ unsigned short f2bf(float x) {
  unsigned u = __float_as_uint(x);
  u = (u + 0x7FFFu + ((u >> 16) & 1u)) >> 16;
  return (unsigned short)u;
}
__device__ __forceinline__ float bf2f(unsigned short u) {
  return __uint_as_float(((unsigned)u) << 16);
}

// Normalize each (b,v) row, write bf16 X in anchor order (n = v*B + b), fill labN. No atomics.
__global__ void norm_kernel(const float* __restrict__ feat,
                            const int* __restrict__ labels,
                            unsigned short* __restrict__ X,
                            int* __restrict__ labN) {
  int n = blockIdx.x * 4 + (threadIdx.x >> 6);
  int l = threadIdx.x & 63;
  int b = n & (B_IN - 1);
  int v = n >> 12;
  const float4 f = *reinterpret_cast<const float4*>(feat + (size_t)(b * 2 + v) * D_K + l * 4);
  float s = f.x * f.x + f.y * f.y + f.z * f.z + f.w * f.w;
#pragma unroll
  for (int m = 1; m < 64; m <<= 1) s += __shfl_xor(s, m);
  float scale = 1.0f / fmaxf(sqrtf(s), 1e-12f);
  ushort4 o;
  o.x = f2bf(f.x * scale);
  o.y = f2bf(f.y * scale);
  o.z = f2bf(f.z * scale);
  o.w = f2bf(f.w * scale);
  *reinterpret_cast<ushort4*>(X + (size_t)n * D_K + l * 4) = o;
  if (l == 0) labN[n] = labels[b];
}

// Class sums G[c] = sum of normalized rows (both views) with label c, and cnt[c] via popcount.
// 250 blocks x 256 threads; wave w handles class blockIdx*4+w.
__global__ void classsum_kernel(const unsigned short* __restrict__ X,
                                const int* __restrict__ labels,
                                float* __restrict__ G,
                                int* __restrict__ cnt) {
  const int c = blockIdx.x * 4 + (threadIdx.x >> 6);
  const int l = threadIdx.x & 63;
  float a0 = 0.f, a1 = 0.f, a2 = 0.f, a3 = 0.f;
  int count = 0;
  for (int it = 0; it < B_IN / 64; ++it) {
    unsigned long long m = __ballot(labels[it * 64 + l] == c);
    count += __popcll(m);
    while (m) {
      int bit = __ffsll((long long)m) - 1;
      m &= m - 1;
      int b = it * 64 + bit;
      ushort4 r0 = *reinterpret_cast<const ushort4*>(X + (size_t)b * D_K + l * 4);
      ushort4 r1 = *reinterpret_cast<const ushort4*>(X + (size_t)(b + B_IN) * D_K + l * 4);
      a0 += bf2f(r0.x) + bf2f(r1.x);
      a1 += bf2f(r0.y) + bf2f(r1.y);
      a2 += bf2f(r0.z) + bf2f(r1.z);
      a3 += bf2f(r0.w) + bf2f(r1.w);
    }
  }
  float4 o = {a0, a1, a2, a3};
  *reinterpret_cast<float4*>(G + (size_t)c * D_K + l * 4) = o;
  if (l == 0) cnt[c] = count;
}

// Main: 1024 blocks = 32 row-groups (256 rows) x 32 col-splits (256 cols).
// 512 threads = 8 waves; wave w owns rows [rbase + w*32, +32): A resident in 64 VGPRs.
// Cols streamed as 8 tiles of 32 via global_load_lds into 2x16KB LDS dbuf,
// ONE __syncthreads per jt (loads span the whole compute phase). S-only epilogue.
// 8 waves share each staged B tile; 2 blocks/CU co-resident for cross-block overlap.
__global__ __launch_bounds__(512, 2) void main_kernel(const unsigned short* __restrict__ X,
                                                      float* __restrict__ SpA) {
  __shared__ __align__(16) char Bs[2][16384];
  const int tid = threadIdx.x;
  const int l = tid & 63, w = tid >> 6;
  const int lm = l & 15, lh = l >> 4;
  const int rg = blockIdx.x >> 5;   // 32 row groups of 256
  const int cs = blockIdx.x & 31;   // 32 col splits of 256
  const int rbase = rg * 256;
  const int cbase = cs * 256;
  const int wrow = rbase + w * 32;
  const int4* Xg = reinterpret_cast<const int4*>(X);  // 32 int4 per row

  // stage jt=0 into Bs[0]: 32 X-rows x 512B = 1024 int4; 2 issues x 512 threads.
  // Source pre-swizzled (slot e -> e^(row&7)); LDS dest linear (wave-uniform base + lane*16).
#pragma unroll
  for (int i = 0; i < 2; ++i) {
    int c = i * 512 + tid;
    int row = c >> 5;
    int c16s = (c & 31) ^ (row & 7);
    const int4* g = Xg + (size_t)(cbase + row) * 32 + c16s;
    char* s = &Bs[0][0] + (size_t)(i * 512 + (w << 6)) * 16;
    __builtin_amdgcn_global_load_lds((glob_uint*)g, (lds_uint*)s, 16, 0, 0);
  }

  // A fragments: rows wrow + fi*16 + lm, elems kk*32 + lh*8 .. +7 (resident; R7: VGPR 84)
  bf16x8 a[2][8];
#pragma unroll
  for (int fi = 0; fi < 2; ++fi)
#pragma unroll
    for (int kk = 0; kk < 8; ++kk) {
      a[fi][kk] = *reinterpret_cast<const bf16x8*>(
          X + (size_t)(wrow + fi * 16 + lm) * D_K + kk * 32 + lh * 8);
      asm volatile("" : "+v"(a[fi][kk]));  // forbid remat
    }

  float S[2][4] = {};

  __syncthreads();  // jt=0 staged

  for (int jt = 0; jt < 8; ++jt) {
    const int cur = jt & 1;
    // stage jt+1 into the other buffer (readers passed the previous barrier);
    // implicit vmcnt(0) at the END-of-jt barrier gives loads the full phase to land.
    if (jt < 7) {
      char* buf = &Bs[cur ^ 1][0];
      const int col0 = cbase + (jt + 1) * 32;
#pragma unroll
      for (int i = 0; i < 2; ++i) {
        int c = i * 512 + tid;
        int row = c >> 5;
        int c16s = (c & 31) ^ (row & 7);
        const int4* g = Xg + (size_t)(col0 + row) * 32 + c16s;
        char* s = buf + (size_t)(i * 512 + (w << 6)) * 16;
        __builtin_amdgcn_global_load_lds((glob_uint*)g, (lds_uint*)s, 16, 0, 0);
      }
    }

    const char* bufc = &Bs[cur][0];
    f32x4 acc[2][2];
#pragma unroll
    for (int fi = 0; fi < 2; ++fi) {
      acc[fi][0] = (f32x4){0.f, 0.f, 0.f, 0.f};
      acc[fi][1] = (f32x4){0.f, 0.f, 0.f, 0.f};
    }
    const int ba0 = lm * 512, sw0 = (lm & 7) << 4;
    const int ba1 = (lm + 16) * 512;  // +16 rows: same low-3 bits -> same swizzle
    __builtin_amdgcn_s_setprio(1);
#pragma unroll
    for (int kk = 0; kk < 8; ++kk) {
      int ko = (kk * 64 + lh * 16) ^ sw0;
      bf16x8 b0 = *reinterpret_cast<const bf16x8*>(bufc + ba0 + ko);
      bf16x8 b1 = *reinterpret_cast<const bf16x8*>(bufc + ba1 + ko);
#pragma unroll
      for (int fi = 0; fi < 2; ++fi) {
        acc[fi][0] = __builtin_amdgcn_mfma_f32_16x16x32_bf16(a[fi][kk], b0, acc[fi][0], 0, 0, 0);
        acc[fi][1] = __builtin_amdgcn_mfma_f32_16x16x32_bf16(a[fi][kk], b1, acc[fi][1], 0, 0, 0);
      }
    }
    __builtin_amdgcn_s_setprio(0);
    // epilogue: S += exp(2v-2) = exp2(C*v - C) over ALL cols (self removed analytically later)
#pragma unroll
    for (int fi = 0; fi < 2; ++fi)
#pragma unroll
      for (int fj = 0; fj < 2; ++fj)
#pragma unroll
        for (int r = 0; r < 4; ++r)
          S[fi][r] += exp2f(fmaf(acc[fi][fj][r], EXPC, -EXPC));
    __syncthreads();
  }

  // reduce across the 16 lm lanes; write Sp[row][split] (coalesced for reduceA)
#pragma unroll
  for (int fi = 0; fi < 2; ++fi)
#pragma unroll
    for (int r = 0; r < 4; ++r) {
      float s = S[fi][r];
#pragma unroll
      for (int m = 1; m < 16; m <<= 1) s += __shfl_xor(s, m);
      if (lm == 0) {
        int row = wrow + fi * 16 + lh * 4 + r;
        SpA[(size_t)row * NSPLIT + cs] = s;
      }
    }
}

// Per-anchor loss + final mean: one wave per 16 anchors; block partial -> one atomicAdd.
__global__ void reduceA_kernel(const float* __restrict__ Sp,
                               const unsigned short* __restrict__ X,
                               const float* __restrict__ G,
                               const int* __restrict__ labN,
                               const int* __restrict__ cnt,
                               float* __restrict__ out) {
  __shared__ float red[4];
  const int w = threadIdx.x >> 6, l = threadIdx.x & 63;
  const int gw = blockIdx.x * 4 + w;  // 0..511
  float bacc = 0.f;
  for (int k = 0; k < 16; ++k) {
    int n = gw * 16 + k;
    int lab = labN[n];
    ushort4 xr = *reinterpret_cast<const ushort4*>(X + (size_t)n * D_K + l * 4);
    float4 gr = *reinterpret_cast<const float4*>(G + (size_t)lab * D_K + l * 4);
    float dp = bf2f(xr.x) * gr.x + bf2f(xr.y) * gr.y + bf2f(xr.z) * gr.z + bf2f(xr.w) * gr.w;
    float sl = (l < NSPLIT) ? Sp[(size_t)n * NSPLIT + l] : 0.f;
#pragma unroll
    for (int m = 1; m < 64; m <<= 1) {
      dp += __shfl_xor(dp, m);
      sl += __shfl_xor(sl, m);
    }
    if (l == 0) {
      float S = sl - 1.0f;            // remove self exp term (exp(2*selfdot-2) ~= 1)
      float P = 2.0f * dp - 2.0f;     // G includes self; remove self logit (~= 2)
      float np = (float)(2 * cnt[lab] - 1);
      bacc += logf(S) + 2.0f - P / np;
    }
  }
  if (l == 0) red[w] = bacc;
  __syncthreads();
  if (threadIdx.x == 0)
    atomicAdd(out, (red[0] + red[1] + red[2] + red[3]) * (1.0f / (float)N_TOT));
}

extern "C" void kernel_launch(void* const* d_in, const int* in_sizes, int n_in,
                              void* d_out, int out_size, void* d_ws, size_t ws_size,
                              hipStream_t stream) {
  const float* feat = (const float*)d_in[0];
  const int* labels = (const int*)d_in[1];
  char* ws = (char*)d_ws;
  unsigned short* X = (unsigned short*)ws;   // 4 MB
  int* labN = (int*)(ws + 4194304);          // 32 KB
  int* cnt = (int*)(ws + 4227072);           // 4 KB
  float* Sp = (float*)(ws + 4231168);        // 8192*32*4 = 1 MB
  float* G = (float*)(ws + 5279744);         // 1000*256*4 = 1000 KB
  float* out = (float*)d_out;

  hipMemsetAsync(out, 0, sizeof(float), stream);
  norm_kernel<<<2048, 256, 0, stream>>>(feat, labels, X, labN);
  classsum_kernel<<<250, 256, 0, stream>>>(X, labels, G, cnt);
  main_kernel<<<NRG * NSPLIT, 512, 0, stream>>>(X, Sp);
  reduceA_kernel<<<128, 256, 0, stream>>>(Sp, X, G, labN, cnt, out);
}

// Round 13
// 103.236 us; speedup vs baseline: 1.2119x; 1.0411x over previous
//
#include <hip/hip_runtime.h>
#include <hip/hip_bf16.h>

typedef __attribute__((ext_vector_type(8))) short bf16x8;
typedef __attribute__((ext_vector_type(4))) float f32x4;

#define N_TOT 8192
#define B_IN  4096
#define D_K   256
#define NSPLIT 32   // col splits of 256
#define NPANEL 64   // row panels of 128
#define EXPC 2.8853900817779268f  // 2/ln2

typedef __attribute__((address_space(3))) unsigned int lds_uint;
typedef __attribute__((address_space(1))) const unsigned int glob_uint;

__device__ __forceinline__ unsigned short f2bf(float x) {
  unsigned u = __float_as_uint(x);
  u = (u + 0x7FFFu + ((u >> 16) & 1u)) >> 16;
  return (unsigned short)u;
}
__device__ __forceinline__ float bf2f(unsigned short u) {
  return __uint_as_float(((unsigned)u) << 16);
}

// Normalize each (b,v) row, write bf16 X in anchor order (n = v*B + b), fill labN. No atomics.
__global__ void norm_kernel(const float* __restrict__ feat,
                            const int* __restrict__ labels,
                            unsigned short* __restrict__ X,
                            int* __restrict__ labN) {
  int n = blockIdx.x * 4 + (threadIdx.x >> 6);
  int l = threadIdx.x & 63;
  int b = n & (B_IN - 1);
  int v = n >> 12;
  const float4 f = *reinterpret_cast<const float4*>(feat + (size_t)(b * 2 + v) * D_K + l * 4);
  float s = f.x * f.x + f.y * f.y + f.z * f.z + f.w * f.w;
#pragma unroll
  for (int m = 1; m < 64; m <<= 1) s += __shfl_xor(s, m);
  float scale = 1.0f / fmaxf(sqrtf(s), 1e-12f);
  ushort4 o;
  o.x = f2bf(f.x * scale);
  o.y = f2bf(f.y * scale);
  o.z = f2bf(f.z * scale);
  o.w = f2bf(f.w * scale);
  *reinterpret_cast<ushort4*>(X + (size_t)n * D_K + l * 4) = o;
  if (l == 0) labN[n] = labels[b];
}

// Class sums G[c] = sum of normalized rows (both views) with label c, and cnt[c] via popcount.
// 250 blocks x 256 threads; wave w handles class blockIdx*4+w.
__global__ void classsum_kernel(const unsigned short* __restrict__ X,
                                const int* __restrict__ labels,
                                float* __restrict__ G,
                                int* __restrict__ cnt) {
  const int c = blockIdx.x * 4 + (threadIdx.x >> 6);
  const int l = threadIdx.x & 63;
  float a0 = 0.f, a1 = 0.f, a2 = 0.f, a3 = 0.f;
  int count = 0;
  for (int it = 0; it < B_IN / 64; ++it) {
    unsigned long long m = __ballot(labels[it * 64 + l] == c);
    count += __popcll(m);
    while (m) {
      int bit = __ffsll((long long)m) - 1;
      m &= m - 1;
      int b = it * 64 + bit;
      ushort4 r0 = *reinterpret_cast<const ushort4*>(X + (size_t)b * D_K + l * 4);
      ushort4 r1 = *reinterpret_cast<const ushort4*>(X + (size_t)(b + B_IN) * D_K + l * 4);
      a0 += bf2f(r0.x) + bf2f(r1.x);
      a1 += bf2f(r0.y) + bf2f(r1.y);
      a2 += bf2f(r0.z) + bf2f(r1.z);
      a3 += bf2f(r0.w) + bf2f(r1.w);
    }
  }
  float4 o = {a0, a1, a2, a3};
  *reinterpret_cast<float4*>(G + (size_t)c * D_K + l * 4) = o;
  if (l == 0) cnt[c] = count;
}

// Main: R7 structure (best measured: 60us) + XCD split-colocation + S-only epilogue.
// 2048 blocks; remap so blocks with raw%8==k (same XCD by round-robin) share the SAME
// 4 col-splits -> per-XCD L2 hot set ~1.6MB < 4MB -> B staging hits L2 (~200cyc) not L3.
// 256 threads = 4 waves; wave w owns rows [rbase + w*32, +32): A resident in 64 VGPRs.
// Cols streamed as 8 tiles of 32 via global_load_lds into 2x16KB LDS dbuf, 1 barrier/jt.
__global__ __launch_bounds__(256, 2) void main_kernel(const unsigned short* __restrict__ X,
                                                      float* __restrict__ SpA) {
  __shared__ __align__(16) char Bs[2][16384];
  const int tid = threadIdx.x;
  const int l = tid & 63, w = tid >> 6;
  const int lm = l & 15, lh = l >> 4;
  const int raw = blockIdx.x;
  const int rg = raw >> 5;                             // 64 panels of 128 rows
  const int cs = ((raw & 7) << 2) | ((raw >> 3) & 3);  // XCD-colocated split group
  const int rbase = rg * 128;
  const int cbase = cs * 256;
  const int wrow = rbase + w * 32;
  const int4* Xg = reinterpret_cast<const int4*>(X);  // 32 int4 per row

  // stage jt=0 into Bs[0]: 32 X-rows x 512B = 1024 int4; 4 issues x 256 threads.
  // Source pre-swizzled (slot e -> e^(row&7)); LDS dest linear (wave-uniform base + lane*16).
#pragma unroll
  for (int i = 0; i < 4; ++i) {
    int c = i * 256 + tid;
    int row = c >> 5;
    int c16s = (c & 31) ^ (row & 7);
    const int4* g = Xg + (size_t)(cbase + row) * 32 + c16s;
    char* s = &Bs[0][0] + (size_t)(i * 256 + (w << 6)) * 16;
    __builtin_amdgcn_global_load_lds((glob_uint*)g, (lds_uint*)s, 16, 0, 0);
  }

  // A fragments: rows wrow + fi*16 + lm, elems kk*32 + lh*8 .. +7 (resident)
  bf16x8 a[2][8];
#pragma unroll
  for (int fi = 0; fi < 2; ++fi)
#pragma unroll
    for (int kk = 0; kk < 8; ++kk) {
      a[fi][kk] = *reinterpret_cast<const bf16x8*>(
          X + (size_t)(wrow + fi * 16 + lm) * D_K + kk * 32 + lh * 8);
      asm volatile("" : "+v"(a[fi][kk]));  // forbid remat
    }

  float S[2][4] = {};

  __syncthreads();  // jt=0 staged

  for (int jt = 0; jt < 8; ++jt) {
    const int cur = jt & 1;
    // stage jt+1 into the other buffer; the END-of-jt barrier's implicit vmcnt(0)
    // gives these loads the whole compute phase to land.
    if (jt < 7) {
      char* buf = &Bs[cur ^ 1][0];
      const int col0 = cbase + (jt + 1) * 32;
#pragma unroll
      for (int i = 0; i < 4; ++i) {
        int c = i * 256 + tid;
        int row = c >> 5;
        int c16s = (c & 31) ^ (row & 7);
        const int4* g = Xg + (size_t)(col0 + row) * 32 + c16s;
        char* s = buf + (size_t)(i * 256 + (w << 6)) * 16;
        __builtin_amdgcn_global_load_lds((glob_uint*)g, (lds_uint*)s, 16, 0, 0);
      }
    }

    const char* bufc = &Bs[cur][0];
    f32x4 acc[2][2];
#pragma unroll
    for (int fi = 0; fi < 2; ++fi) {
      acc[fi][0] = (f32x4){0.f, 0.f, 0.f, 0.f};
      acc[fi][1] = (f32x4){0.f, 0.f, 0.f, 0.f};
    }
    const int ba0 = lm * 512, sw0 = (lm & 7) << 4;
    const int ba1 = (lm + 16) * 512;  // +16 rows: same low-3 bits -> same swizzle
#pragma unroll
    for (int kk = 0; kk < 8; ++kk) {
      int ko = (kk * 64 + lh * 16) ^ sw0;
      bf16x8 b0 = *reinterpret_cast<const bf16x8*>(bufc + ba0 + ko);
      bf16x8 b1 = *reinterpret_cast<const bf16x8*>(bufc + ba1 + ko);
#pragma unroll
      for (int fi = 0; fi < 2; ++fi) {
        acc[fi][0] = __builtin_amdgcn_mfma_f32_16x16x32_bf16(a[fi][kk], b0, acc[fi][0], 0, 0, 0);
        acc[fi][1] = __builtin_amdgcn_mfma_f32_16x16x32_bf16(a[fi][kk], b1, acc[fi][1], 0, 0, 0);
      }
    }
    // epilogue: S += exp(2v-2) = exp2(C*v - C) over ALL cols (self removed analytically later)
#pragma unroll
    for (int fi = 0; fi < 2; ++fi)
#pragma unroll
      for (int fj = 0; fj < 2; ++fj)
#pragma unroll
        for (int r = 0; r < 4; ++r)
          S[fi][r] += exp2f(fmaf(acc[fi][fj][r], EXPC, -EXPC));
    __syncthreads();
  }

  // reduce across the 16 lm lanes; write Sp[row][split] (coalesced for reduceA)
#pragma unroll
  for (int fi = 0; fi < 2; ++fi)
#pragma unroll
    for (int r = 0; r < 4; ++r) {
      float s = S[fi][r];
#pragma unroll
      for (int m = 1; m < 16; m <<= 1) s += __shfl_xor(s, m);
      if (lm == 0) {
        int row = wrow + fi * 16 + lh * 4 + r;
        SpA[(size_t)row * NSPLIT + cs] = s;
      }
    }
}

// Per-anchor loss + final mean: one wave per 16 anchors; block partial -> one atomicAdd.
__global__ void reduceA_kernel(const float* __restrict__ Sp,
                               const unsigned short* __restrict__ X,
                               const float* __restrict__ G,
                               const int* __restrict__ labN,
                               const int* __restrict__ cnt,
                               float* __restrict__ out) {
  __shared__ float red[4];
  const int w = threadIdx.x >> 6, l = threadIdx.x & 63;
  const int gw = blockIdx.x * 4 + w;  // 0..511
  float bacc = 0.f;
  for (int k = 0; k < 16; ++k) {
    int n = gw * 16 + k;
    int lab = labN[n];
    ushort4 xr = *reinterpret_cast<const ushort4*>(X + (size_t)n * D_K + l * 4);
    float4 gr = *reinterpret_cast<const float4*>(G + (size_t)lab * D_K + l * 4);
    float dp = bf2f(xr.x) * gr.x + bf2f(xr.y) * gr.y + bf2f(xr.z) * gr.z + bf2f(xr.w) * gr.w;
    float sl = (l < NSPLIT) ? Sp[(size_t)n * NSPLIT + l] : 0.f;
#pragma unroll
    for (int m = 1; m < 64; m <<= 1) {
      dp += __shfl_xor(dp, m);
      sl += __shfl_xor(sl, m);
    }
    if (l == 0) {
      float S = sl - 1.0f;            // remove self exp term (exp(2*selfdot-2) ~= 1)
      float P = 2.0f * dp - 2.0f;     // G includes self; remove self logit (~= 2)
      float np = (float)(2 * cnt[lab] - 1);
      bacc += logf(S) + 2.0f - P / np;
    }
  }
  if (l == 0) red[w] = bacc;
  __syncthreads();
  if (threadIdx.x == 0)
    atomicAdd(out, (red[0] + red[1] + red[2] + red[3]) * (1.0f / (float)N_TOT));
}

extern "C" void kernel_launch(void* const* d_in, const int* in_sizes, int n_in,
                              void* d_out, int out_size, void* d_ws, size_t ws_size,
                              hipStream_t stream) {
  const float* feat = (const float*)d_in[0];
  const int* labels = (const int*)d_in[1];
  char* ws = (char*)d_ws;
  unsigned short* X = (unsigned short*)ws;   // 4 MB
  int* labN = (int*)(ws + 4194304);          // 32 KB
  int* cnt = (int*)(ws + 4227072);           // 4 KB
  float* Sp = (float*)(ws + 4231168);        // 8192*32*4 = 1 MB
  float* G = (float*)(ws + 5279744);         // 1000*256*4 = 1000 KB
  float* out = (float*)d_out;

  hipMemsetAsync(out, 0, sizeof(float), stream);
  norm_kernel<<<2048, 256, 0, stream>>>(feat, labels, X, labN);
  classsum_kernel<<<250, 256, 0, stream>>>(X, labels, G, cnt);
  main_kernel<<<NPANEL * NSPLIT, 256, 0, stream>>>(X, Sp);
  reduceA_kernel<<<128, 256, 0, stream>>>(Sp, X, G, labN, cnt, out);
}